// Round 7
// baseline (17.504 us; speedup 1.0000x reference)
//
#include <hip/hip_runtime.h>

// votes[b,n,m,o] = sum_i inputs[b,n,i] * W[n,m,i,o]
// B=64, N_IN=1152, N_OUT=10, D_IN=8, D_OUT=16
// R6 post-mortem: W re-read volume is free (KB 8->16 neutral); nt store = -1.6us.
// R7: KB=64 — each thread reads its W column exactly ONCE (compulsory-only W
// traffic, 5.9 MB), loops all 64 b. 64-thread blocks (720 single-wave blocks)
// spread over all CUs. If this is neutral too, we're at fixed-overhead floor.

typedef float floatx4 __attribute__((ext_vector_type(4)));

constexpr int B     = 64;
constexpr int N_IN  = 1152;
constexpr int N_OUT = 10;
constexpr int D_IN  = 8;
constexpr int D_OUT = 16;
constexpr int NT4   = N_IN * N_OUT * 4;        // 46080 (n,m,o4) positions
constexpr int BLOCK = 64;                      // one wave per block
constexpr int NBLOCKS = NT4 / BLOCK;           // 720

__global__ __launch_bounds__(BLOCK)
void Transforming_56195352101061_kernel(const float* __restrict__ in,
                                        const float* __restrict__ W,
                                        float* __restrict__ out) {
    int tid = blockIdx.x * BLOCK + (int)threadIdx.x;  // [0, 46080)
    int o4  = tid & 3;
    int lin = tid >> 2;
    int m   = lin % N_OUT;
    int n   = lin / N_OUT;

    // This thread's W column, read exactly once: 8 float4s (128 B).
    const float* wbase = W + ((size_t)(n * N_OUT + m) * D_IN) * D_OUT + o4 * 4;
    floatx4 w[D_IN];
#pragma unroll
    for (int i = 0; i < D_IN; ++i)
        w[i] = *reinterpret_cast<const floatx4*>(wbase + i * D_OUT);

    const float* ibase = in + (size_t)n * D_IN;           // + b*N_IN*D_IN per j
    floatx4* out4 = reinterpret_cast<floatx4*>(out) + tid; // + b*NT4 per j

#pragma unroll 8
    for (int b = 0; b < B; ++b) {
        const floatx4* iv = reinterpret_cast<const floatx4*>(
            ibase + (size_t)b * N_IN * D_IN);
        floatx4 i0 = iv[0];
        floatx4 i1 = iv[1];
        float ivals[8] = {i0.x, i0.y, i0.z, i0.w, i1.x, i1.y, i1.z, i1.w};

        floatx4 acc = {0.f, 0.f, 0.f, 0.f};
#pragma unroll
        for (int i = 0; i < D_IN; ++i)
            acc += ivals[i] * w[i];

        __builtin_nontemporal_store(acc, out4 + (size_t)b * NT4);
    }
}

extern "C" void kernel_launch(void* const* d_in, const int* in_sizes, int n_in,
                              void* d_out, int out_size, void* d_ws, size_t ws_size,
                              hipStream_t stream) {
    const float* in = (const float*)d_in[0];   // [B, N_IN, 8, 1]
    const float* W  = (const float*)d_in[1];   // [1, N_IN, N_OUT, 8, 16, 1]
    float* out      = (float*)d_out;           // [B, N_IN, N_OUT, 16, 1]

    Transforming_56195352101061_kernel<<<NBLOCKS, BLOCK, 0, stream>>>(in, W, out);
}

// Round 8
// 14.397 us; speedup vs baseline: 1.2159x; 1.2159x over previous
//
#include <hip/hip_runtime.h>

// votes[b,n,m,o] = sum_i inputs[b,n,i] * W[n,m,i,o]
// B=64, N_IN=1152, N_OUT=10, D_IN=8, D_OUT=16
// Ladder: R1 KB=1 23.4 | R2 KB=8 15.7 | R4 +swz+nt 14.1 | R6 KB=16 14.2 |
// R7 KB=64 (720 waves) 17.5. W re-read volume free; TLP matters; nt = -1.6us.
// R8: KB=4 -> 11520 waves (8+/SIMD, CU-saturating) to test upward-TLP.
// Swizzle keeps all 16 bb-replicas of a chunk on one XCD (W slice 0.74MB).

typedef float floatx4 __attribute__((ext_vector_type(4)));

constexpr int B     = 64;
constexpr int N_IN  = 1152;
constexpr int N_OUT = 10;
constexpr int D_IN  = 8;
constexpr int D_OUT = 16;
constexpr int KB    = 4;                       // b values per thread
constexpr int NBB   = B / KB;                  // 16 batch groups
constexpr int NCHUNK = N_IN * N_OUT * 4 / 256; // 180 chunks of 256 threads
constexpr int NBLOCKS = NCHUNK * NBB;          // 2880
constexpr int MAIN  = 176 * NBB;               // 2816 swizzled blocks

__global__ __launch_bounds__(256)
void Transforming_56195352101061_kernel(const float* __restrict__ in,
                                        const float* __restrict__ W,
                                        float* __restrict__ out) {
    // Swizzle: all NBB batch-replicas of chunk c satisfy blockIdx%8 == c%8,
    // so they share one XCD's L2 (assuming xcd = dispatch_order % 8).
    int id = blockIdx.x;
    int bb, c;
    if (id < MAIN) {                 // id = 128g + 8*bb + r,  c = 8g + r
        int r = id & 7;
        int t = id >> 3;
        bb    = t & 15;
        c     = (t >> 4) * 8 + r;    // g in [0,22)
    } else {                         // tail: c in [176,180)
        int k = id - MAIN;
        bb    = k >> 2;
        c     = 176 + (k & 3);
    }

    int tid = c * 256 + (int)threadIdx.x;   // [0, 46080) over (n,m,o4)
    int o4  = tid & 3;
    int lin = tid >> 2;
    int m   = lin % N_OUT;
    int n   = lin / N_OUT;

    // Load this thread's W column once: 8 float4s (one per i).
    const float* wbase = W + ((size_t)(n * N_OUT + m) * D_IN) * D_OUT + o4 * 4;
    floatx4 w[D_IN];
#pragma unroll
    for (int i = 0; i < D_IN; ++i)
        w[i] = *reinterpret_cast<const floatx4*>(wbase + i * D_OUT);

    const float* ibase = in + ((size_t)(bb * KB) * N_IN + n) * D_IN;
    floatx4* out4 = reinterpret_cast<floatx4*>(out);
    size_t obase = ((size_t)((bb * KB) * N_IN + n) * N_OUT + m) * 4 + o4;
    constexpr size_t OB_STRIDE = (size_t)N_IN * N_OUT * 4;  // float4s per b

#pragma unroll
    for (int j = 0; j < KB; ++j) {
        const floatx4* iv = reinterpret_cast<const floatx4*>(
            ibase + (size_t)j * N_IN * D_IN);
        floatx4 i0 = iv[0];
        floatx4 i1 = iv[1];
        float ivals[8] = {i0.x, i0.y, i0.z, i0.w, i1.x, i1.y, i1.z, i1.w};

        floatx4 acc = {0.f, 0.f, 0.f, 0.f};
#pragma unroll
        for (int i = 0; i < D_IN; ++i)
            acc += ivals[i] * w[i];

        __builtin_nontemporal_store(acc, &out4[obase + (size_t)j * OB_STRIDE]);
    }
}

extern "C" void kernel_launch(void* const* d_in, const int* in_sizes, int n_in,
                              void* d_out, int out_size, void* d_ws, size_t ws_size,
                              hipStream_t stream) {
    const float* in = (const float*)d_in[0];   // [B, N_IN, 8, 1]
    const float* W  = (const float*)d_in[1];   // [1, N_IN, N_OUT, 8, 16, 1]
    float* out      = (float*)d_out;           // [B, N_IN, N_OUT, 16, 1]

    Transforming_56195352101061_kernel<<<NBLOCKS, 256, 0, stream>>>(in, W, out);
}

// Round 9
// 14.166 us; speedup vs baseline: 1.2357x; 1.0163x over previous
//
#include <hip/hip_runtime.h>

// votes[b,n,m,o] = sum_i inputs[b,n,i] * W[n,m,i,o]
// B=64, N_IN=1152, N_OUT=10, D_IN=8, D_OUT=16
//
// Final configuration (measured best, R4 = 14.1 us):
//   KB=8, XCD-aware swizzle, non-temporal dwordx4 stores.
// Ladder: KB=1 23.4 | KB=8 15.7 | +swz+nt 14.1 | KB=16 14.2 | KB=64 17.5 |
//         KB=4 14.4.
// Roofline: 55.5 MB compulsory traffic @ 6.5-6.7 TB/s (fill-proven) = 8.5 us;
// residual ~5.5 us is launch ramp + cold-load latency + graph-replay overhead,
// invariant under KB/swizzle/TLP sweeps -> practical floor for this shape.

typedef float floatx4 __attribute__((ext_vector_type(4)));

constexpr int B     = 64;
constexpr int N_IN  = 1152;
constexpr int N_OUT = 10;
constexpr int D_IN  = 8;
constexpr int D_OUT = 16;
constexpr int KB    = 8;                       // b values per thread
constexpr int NCHUNK = N_IN * N_OUT * 4 / 256; // 180 chunks of 256 threads
constexpr int NBLOCKS = NCHUNK * (B / KB);     // 1440

__global__ __launch_bounds__(256)
void Transforming_56195352101061_kernel(const float* __restrict__ in,
                                        const float* __restrict__ W,
                                        float* __restrict__ out) {
    // Swizzle: blockIdx.x -> (bb, c) such that blockIdx.x % 8 is a function
    // of c only (for the first 1408 blocks). All 8 bb-replicas of chunk c
    // then land on the same XCD (assuming xcd = dispatch_order % 8).
    int id = blockIdx.x;
    int bb, c;
    if (id < 1408) {                 // 8 r * 8 bb * 22 g
        int r = id & 7;
        int t = id >> 3;
        bb    = t & 7;
        c     = (t >> 3) * 8 + r;    // c = 8g + r, g in [0,22)
    } else {                         // tail: c in [176,180), 2% of blocks
        int k = id - 1408;
        bb    = k >> 2;
        c     = 176 + (k & 3);
    }

    int tid = c * 256 + (int)threadIdx.x;   // [0, 46080) over (n,m,o4)
    int o4  = tid & 3;
    int lin = tid >> 2;
    int m   = lin % N_OUT;
    int n   = lin / N_OUT;

    // Load this thread's W column once: 8 float4s (one per i). L2-resident.
    const float* wbase = W + ((size_t)(n * N_OUT + m) * D_IN) * D_OUT + o4 * 4;
    floatx4 w[D_IN];
#pragma unroll
    for (int i = 0; i < D_IN; ++i)
        w[i] = *reinterpret_cast<const floatx4*>(wbase + i * D_OUT);

    const float* ibase = in + ((size_t)(bb * KB) * N_IN + n) * D_IN;
    floatx4* out4 = reinterpret_cast<floatx4*>(out);
    size_t obase = ((size_t)((bb * KB) * N_IN + n) * N_OUT + m) * 4 + o4;
    constexpr size_t OB_STRIDE = (size_t)N_IN * N_OUT * 4;  // float4s per b

#pragma unroll
    for (int j = 0; j < KB; ++j) {
        const floatx4* iv = reinterpret_cast<const floatx4*>(
            ibase + (size_t)j * N_IN * D_IN);
        floatx4 i0 = iv[0];
        floatx4 i1 = iv[1];
        float ivals[8] = {i0.x, i0.y, i0.z, i0.w, i1.x, i1.y, i1.z, i1.w};

        floatx4 acc = {0.f, 0.f, 0.f, 0.f};
#pragma unroll
        for (int i = 0; i < D_IN; ++i)
            acc += ivals[i] * w[i];

        // Streaming store: proven -1.6us (write stream otherwise thrashes L2).
        __builtin_nontemporal_store(acc, &out4[obase + (size_t)j * OB_STRIDE]);
    }
}

extern "C" void kernel_launch(void* const* d_in, const int* in_sizes, int n_in,
                              void* d_out, int out_size, void* d_ws, size_t ws_size,
                              hipStream_t stream) {
    const float* in = (const float*)d_in[0];   // [B, N_IN, 8, 1]
    const float* W  = (const float*)d_in[1];   // [1, N_IN, N_OUT, 8, 16, 1]
    float* out      = (float*)d_out;           // [B, N_IN, N_OUT, 16, 1]

    Transforming_56195352101061_kernel<<<NBLOCKS, 256, 0, stream>>>(in, W, out);
}